// Round 5
// baseline (328.668 us; speedup 1.0000x reference)
//
#include <hip/hip_runtime.h>
#include <math.h>

#define NNODE  200000
#define DIM    64
#define NF     4
#define NLAYER 2
#define KK     32
#define BB     1024

typedef __bf16 bf16x8 __attribute__((ext_vector_type(8)));
typedef float  f32x4  __attribute__((ext_vector_type(4)));

// Kernel 1: W1 (128x64 f32, row-major) -> W1T bf16 (64 x 128): w1t[d*128+i] = W1[i][d]
__global__ void prep_w1t(const float* __restrict__ W1, __bf16* __restrict__ w1t) {
    int j = blockIdx.x * 256 + threadIdx.x;   // 0..8191
    int d = j >> 7, i = j & 127;
    w1t[j] = (__bf16)W1[i * 64 + d];
}

// One block per (tower, b); each wave (= factor) processes BOTH layers,
// software-pipelined: gathers for layer u+1 are issued before layer u's
// data is consumed, so the memory pipe never idles during compute.
// W1 fragments / b1 / W2 / indices are preloaded so no global load occurs
// inside the compute phase (would force a vmcnt(0) drain).
__global__ __launch_bounds__(256, 3) void kgat_pipe(
    const float* __restrict__ node_emb,
    const __bf16* __restrict__ w1t,
    const float* __restrict__ b1,
    const float* __restrict__ W2,
    const int*   __restrict__ users,
    const int*   __restrict__ items,
    const int*   __restrict__ users_triple,
    const int*   __restrict__ items_triple,
    float*       __restrict__ out)
{
    __shared__ float logitS[128];

    const int bid   = blockIdx.x;          // 0..2047
    const int tower = bid >> 10;
    const int b     = bid & 1023;
    const int tid   = threadIdx.x;
    const int w     = tid >> 6;            // wave id = factor
    const int lane  = tid & 63;
    const int m16   = lane & 15;
    const int quad  = lane >> 4;

    const int* __restrict__ triple = tower ? items_triple : users_triple;
    const int* __restrict__ idxarr = tower ? items : users;

    // ---- all edge indices for both layers, issued upfront ----
    int hi[NLAYER][2], ti[NLAYER][2];
#pragma unroll
    for (int u = 0; u < NLAYER; ++u) {
        const int hb = ((b * 3 + 0) * NLAYER + u) * KK;
        const int tb = ((b * 3 + 2) * NLAYER + u) * KK;
        hi[u][0] = triple[hb + m16];
        hi[u][1] = triple[hb + 16 + m16];
        ti[u][0] = triple[tb + m16];
        ti[u][1] = triple[tb + 16 + m16];
    }
    const int oid = idxarr[b];

    // ---- persistent operands: W1 B-fragments (16 VGPR), b1, W2 ----
    bf16x8 Bn[4];
#pragma unroll
    for (int nt = 0; nt < 4; ++nt)
        Bn[nt] = *(const bf16x8*)(w1t + (nt * 16 + m16) * 128 + quad * 8);
    // note: Bn[nt] above only covers kt=0 slice; load full set [nt][kt]:
    bf16x8 Bf[4][4];
#pragma unroll
    for (int nt = 0; nt < 4; ++nt)
#pragma unroll
        for (int kt = 0; kt < 4; ++kt)
            Bf[nt][kt] = *(const bf16x8*)(w1t + (nt * 16 + m16) * 128 + kt * 32 + quad * 8);
    float b1v[4], w2v[4];
#pragma unroll
    for (int nt = 0; nt < 4; ++nt) {
        b1v[nt] = b1[nt * 16 + m16];
        w2v[nt] = W2[nt * 16 + m16];
    }

    // origin row value (issued early, stored at the end)
    const float orv = node_emb[((size_t)oid * NF + w) * DIM + lane];

    // ---- gather landing registers, double-buffered across layers ----
    // L[buf][mt*8 + kt*2 + h] : edge mt*16+m16, dims (kt&1)*32 + quad*8 + h*4 .. +3
    // kt 0,1 = h row ; kt 2,3 = t row
    f32x4 L[2][16];

    // issue gathers for layer 0
#pragma unroll
    for (int mt = 0; mt < 2; ++mt) {
        const float* __restrict__ rh = node_emb + ((size_t)hi[0][mt] * NF + w) * DIM;
        const float* __restrict__ rt = node_emb + ((size_t)ti[0][mt] * NF + w) * DIM;
#pragma unroll
        for (int kt = 0; kt < 4; ++kt) {
            const float* __restrict__ src = (kt < 2 ? rh : rt) + (kt & 1) * 32 + quad * 8;
            L[0][mt * 8 + kt * 2 + 0] = *(const f32x4*)src;
            L[0][mt * 8 + kt * 2 + 1] = *(const f32x4*)(src + 4);
        }
    }

#pragma unroll
    for (int u = 0; u < NLAYER; ++u) {
        // ---- issue gathers for layer u+1 BEFORE consuming layer u ----
        if (u + 1 < NLAYER) {
#pragma unroll
            for (int mt = 0; mt < 2; ++mt) {
                const float* __restrict__ rh = node_emb + ((size_t)hi[u + 1][mt] * NF + w) * DIM;
                const float* __restrict__ rt = node_emb + ((size_t)ti[u + 1][mt] * NF + w) * DIM;
#pragma unroll
                for (int kt = 0; kt < 4; ++kt) {
                    const float* __restrict__ src = (kt < 2 ? rh : rt) + (kt & 1) * 32 + quad * 8;
                    L[u + 1][mt * 8 + kt * 2 + 0] = *(const f32x4*)src;
                    L[u + 1][mt * 8 + kt * 2 + 1] = *(const f32x4*)(src + 4);
                }
            }
        }

        // ---- convert layer u's landing regs to MFMA A-fragments (bf16) ----
        bf16x8 Af[2][4];
#pragma unroll
        for (int mt = 0; mt < 2; ++mt)
#pragma unroll
            for (int kt = 0; kt < 4; ++kt) {
                f32x4 v0 = L[u][mt * 8 + kt * 2 + 0];
                f32x4 v1 = L[u][mt * 8 + kt * 2 + 1];
                bf16x8 a;
#pragma unroll
                for (int t = 0; t < 4; ++t) { a[t] = (__bf16)v0[t]; a[4 + t] = (__bf16)v1[t]; }
                Af[mt][kt] = a;
            }

        // ---- MFMA: hid[edge][d] for this wave's 32 edges ----
        f32x4 C[2][4];
#pragma unroll
        for (int mt = 0; mt < 2; ++mt)
#pragma unroll
            for (int nt = 0; nt < 4; ++nt) C[mt][nt] = (f32x4)(0.f);
#pragma unroll
        for (int kt = 0; kt < 4; ++kt)
#pragma unroll
            for (int nt = 0; nt < 4; ++nt) {
                C[0][nt] = __builtin_amdgcn_mfma_f32_16x16x32_bf16(Af[0][kt], Bf[nt][kt], C[0][nt], 0, 0, 0);
                C[1][nt] = __builtin_amdgcn_mfma_f32_16x16x32_bf16(Af[1][kt], Bf[nt][kt], C[1][nt], 0, 0, 0);
            }

        // ---- logits: sum_d relu(hid + b1) * W2  (b2 cancels in softmax) ----
        float lsum[2][4];   // C row = quad*4 + r (edge = mt*16 + row), col = nt*16 + m16
#pragma unroll
        for (int mt = 0; mt < 2; ++mt)
#pragma unroll
            for (int r = 0; r < 4; ++r) {
                float s = 0.f;
#pragma unroll
                for (int nt = 0; nt < 4; ++nt)
                    s += fmaxf(C[mt][nt][r] + b1v[nt], 0.f) * w2v[nt];
                lsum[mt][r] = s;
            }
#pragma unroll
        for (int off = 1; off < 16; off <<= 1)
#pragma unroll
            for (int mt = 0; mt < 2; ++mt)
#pragma unroll
                for (int r = 0; r < 4; ++r)
                    lsum[mt][r] += __shfl_xor(lsum[mt][r], off, 64);

        // intra-wave redistribute via tiny LDS (no barrier: same-wave order)
        if (m16 == 0) {
#pragma unroll
            for (int mt = 0; mt < 2; ++mt) {
                f32x4 v;
#pragma unroll
                for (int r = 0; r < 4; ++r) v[r] = lsum[mt][r];
                *(f32x4*)&logitS[w * 32 + mt * 16 + quad * 4] = v;
            }
        }
        const float lg = logitS[w * 32 + (lane & 31)];

        // ---- softmax over the 32 edges ----
        float mx = lg;
#pragma unroll
        for (int off = 16; off; off >>= 1) mx = fmaxf(mx, __shfl_xor(mx, off, 64));
        const float e = __expf(lg - mx);
        float s = e;
#pragma unroll
        for (int off = 16; off; off >>= 1) s += __shfl_xor(s, off, 64);
        const float wgt = e / s;   // weight for edge k = lane & 31

        // ---- output from registers: out[d] = sum_k w_k * t[k][d] ----
        float o0[8], o1[8];
#pragma unroll
        for (int j = 0; j < 8; ++j) { o0[j] = 0.f; o1[j] = 0.f; }
#pragma unroll
        for (int mt = 0; mt < 2; ++mt) {
            const float wv = __shfl(wgt, mt * 16 + m16, 64);
#pragma unroll
            for (int j = 0; j < 8; ++j) {
                o0[j] += wv * (float)Af[mt][2][j];
                o1[j] += wv * (float)Af[mt][3][j];
            }
        }
#pragma unroll
        for (int off = 1; off < 16; off <<= 1)
#pragma unroll
            for (int j = 0; j < 8; ++j) {
                o0[j] += __shfl_xor(o0[j], off, 64);
                o1[j] += __shfl_xor(o1[j], off, 64);
            }
        if (m16 == 0) {
            float* __restrict__ op =
                out + (((size_t)(tower * 3 + 1 + u) * BB + b) * NF + w) * DIM;
            f32x4 v;
#pragma unroll
            for (int j = 0; j < 4; ++j) v[j] = o0[j];
            *(f32x4*)(op + quad * 8) = v;
#pragma unroll
            for (int j = 0; j < 4; ++j) v[j] = o0[4 + j];
            *(f32x4*)(op + quad * 8 + 4) = v;
#pragma unroll
            for (int j = 0; j < 4; ++j) v[j] = o1[j];
            *(f32x4*)(op + 32 + quad * 8) = v;
#pragma unroll
            for (int j = 0; j < 4; ++j) v[j] = o1[4 + j];
            *(f32x4*)(op + 32 + quad * 8 + 4) = v;
        }
    }

    // origin row
    out[(((size_t)(tower * 3 + 0) * BB + b) * NF + w) * DIM + lane] = orv;
}

extern "C" void kernel_launch(void* const* d_in, const int* in_sizes, int n_in,
                              void* d_out, int out_size, void* d_ws, size_t ws_size,
                              hipStream_t stream) {
    const float* node_emb     = (const float*)d_in[0];
    // d_in[1] = relation_emb — dead in the reference computation
    const float* W1           = (const float*)d_in[2];
    const float* b1           = (const float*)d_in[3];
    const float* W2           = (const float*)d_in[4];
    const float* b2           = (const float*)d_in[5]; (void)b2; // cancels in softmax
    const int*   users        = (const int*)d_in[6];
    const int*   items        = (const int*)d_in[7];
    const int*   users_triple = (const int*)d_in[8];
    const int*   items_triple = (const int*)d_in[9];
    float* out = (float*)d_out;

    __bf16* w1t = (__bf16*)d_ws;   // 64*128*2 = 16 KB

    hipLaunchKernelGGL(prep_w1t, dim3(32), dim3(256), 0, stream, W1, w1t);
    hipLaunchKernelGGL(kgat_pipe, dim3(2 * BB), dim3(256), 0, stream,
                       node_emb, w1t, b1, W2,
                       users, items, users_triple, items_triple, out);
}

// Round 6
// 313.736 us; speedup vs baseline: 1.0476x; 1.0476x over previous
//
#include <hip/hip_runtime.h>
#include <math.h>

#define NNODE  200000
#define DIM    64
#define NF     4
#define NLAYER 2
#define KK     32
#define BB     1024

typedef __bf16 bf16x8 __attribute__((ext_vector_type(8)));
typedef float  f32x4  __attribute__((ext_vector_type(4)));

// LDS row stride: 1 KB row + 16 B pad = 1040 B = 260 dwords (== 4 mod 32:
// fragment reads spread over 8 banks -> ~3x b128, acceptable; the async
// global->LDS write is lane-contiguous, always conflict-free).
#define RSTRIDE_DW 260

// Kernel 1: W1 (128x64 f32, row-major) -> W1T bf16 (64 x 128): w1t[d*128+i] = W1[i][d]
__global__ void prep_w1t(const float* __restrict__ W1, __bf16* __restrict__ w1t) {
    int j = blockIdx.x * 256 + threadIdx.x;   // 0..8191
    int d = j >> 7, i = j & 127;
    w1t[j] = (__bf16)W1[i * 64 + d];
}

// One block per (tower, b, layer); 4 waves, wave w = factor f.
// Gather: 64 node rows (32 h + 32 t), each fetched as ONE contiguous 1 KB
// global_load_lds instruction (64 lanes x 16 B) -> max DRAM page locality.
// Compute: round-4 register path (MFMA + in-register epilogue).
__global__ __launch_bounds__(256, 2) void kgat_lds(
    const float* __restrict__ node_emb,
    const __bf16* __restrict__ w1t,
    const float* __restrict__ b1,
    const float* __restrict__ W2,
    const int*   __restrict__ users,
    const int*   __restrict__ items,
    const int*   __restrict__ users_triple,
    const int*   __restrict__ items_triple,
    float*       __restrict__ out)
{
    __shared__ float Xs[64 * RSTRIDE_DW];   // 66,560 B: rows 0..31 = h, 32..63 = t
    __shared__ float logitS[128];

    const int bid   = blockIdx.x;          // 0..4095
    const int tower = bid >> 11;
    const int b     = (bid >> 1) & 1023;
    const int layer = bid & 1;
    const int tid   = threadIdx.x;
    const int w     = tid >> 6;            // wave id = factor
    const int lane  = tid & 63;
    const int m16   = lane & 15;
    const int quad  = lane >> 4;

    const int* __restrict__ triple = tower ? items_triple : users_triple;
    const int* __restrict__ idxarr = tower ? items : users;

    const int hbase = ((b * 3 + 0) * NLAYER + layer) * KK;
    const int tbase = ((b * 3 + 2) * NLAYER + layer) * KK;

    // ---- async gather: wave w issues rows w*16 .. w*16+15 ----
    // row r < 32 -> h edge r ; row r >= 32 -> t edge r-32. One 1 KB row per
    // instruction: lane reads node_emb[idx*256 + lane*4 ..+3] -> Xs[r*260 + lane*4].
    {
#pragma unroll
        for (int r8 = 0; r8 < 16; ++r8) {
            const int r   = w * 16 + r8;                       // wave-uniform
            const int idx = (r < 32) ? triple[hbase + r] : triple[tbase + r - 32];
            const float* gsrc = node_emb + (size_t)idx * (NF * DIM) + lane * 4;
            __builtin_amdgcn_global_load_lds(
                (const __attribute__((address_space(1))) void*)gsrc,
                (__attribute__((address_space(3))) void*)&Xs[r * RSTRIDE_DW],
                16, 0, 0);
        }
    }

    // ---- persistent operands while gathers fly ----
    bf16x8 Bf[4][4];
#pragma unroll
    for (int nt = 0; nt < 4; ++nt)
#pragma unroll
        for (int kt = 0; kt < 4; ++kt)
            Bf[nt][kt] = *(const bf16x8*)(w1t + (nt * 16 + m16) * 128 + kt * 32 + quad * 8);
    float b1v[4], w2v[4];
#pragma unroll
    for (int nt = 0; nt < 4; ++nt) {
        b1v[nt] = b1[nt * 16 + m16];
        w2v[nt] = W2[nt * 16 + m16];
    }
    const int oid = idxarr[b];
    const float orv = node_emb[((size_t)oid * NF + w) * DIM + lane];

    __syncthreads();   // drains vmcnt (global_load_lds) + makes rows visible

    // ---- A-fragments from LDS (factor w slice), cvt to bf16 ----
    // edge e = mt*16 + m16 ; kt<2 -> h row e ; kt>=2 -> t row 32+e
    bf16x8 Af[2][4];
#pragma unroll
    for (int mt = 0; mt < 2; ++mt) {
        const int e = mt * 16 + m16;
#pragma unroll
        for (int kt = 0; kt < 4; ++kt) {
            const int row = (kt < 2) ? e : (32 + e);
            const float* src = &Xs[row * RSTRIDE_DW + w * 64 + (kt & 1) * 32 + quad * 8];
            f32x4 v0 = *(const f32x4*)src;
            f32x4 v1 = *(const f32x4*)(src + 4);
            bf16x8 a;
#pragma unroll
            for (int u = 0; u < 4; ++u) { a[u] = (__bf16)v0[u]; a[4 + u] = (__bf16)v1[u]; }
            Af[mt][kt] = a;
        }
    }

    // ---- MFMA: hid[edge][d] for this wave's 32 edges ----
    f32x4 C[2][4];
#pragma unroll
    for (int mt = 0; mt < 2; ++mt)
#pragma unroll
        for (int nt = 0; nt < 4; ++nt) C[mt][nt] = (f32x4)(0.f);
#pragma unroll
    for (int kt = 0; kt < 4; ++kt)
#pragma unroll
        for (int nt = 0; nt < 4; ++nt) {
            C[0][nt] = __builtin_amdgcn_mfma_f32_16x16x32_bf16(Af[0][kt], Bf[nt][kt], C[0][nt], 0, 0, 0);
            C[1][nt] = __builtin_amdgcn_mfma_f32_16x16x32_bf16(Af[1][kt], Bf[nt][kt], C[1][nt], 0, 0, 0);
        }

    // ---- logits: sum_d relu(hid + b1) * W2  (b2 cancels in softmax) ----
    float lsum[2][4];   // C row = quad*4 + r (edge = mt*16 + row), col = nt*16 + m16
#pragma unroll
    for (int mt = 0; mt < 2; ++mt)
#pragma unroll
        for (int r = 0; r < 4; ++r) {
            float s = 0.f;
#pragma unroll
            for (int nt = 0; nt < 4; ++nt)
                s += fmaxf(C[mt][nt][r] + b1v[nt], 0.f) * w2v[nt];
            lsum[mt][r] = s;
        }
#pragma unroll
    for (int off = 1; off < 16; off <<= 1)
#pragma unroll
        for (int mt = 0; mt < 2; ++mt)
#pragma unroll
            for (int r = 0; r < 4; ++r)
                lsum[mt][r] += __shfl_xor(lsum[mt][r], off, 64);

    // intra-wave redistribute via tiny LDS (no barrier: same-wave program order)
    if (m16 == 0) {
#pragma unroll
        for (int mt = 0; mt < 2; ++mt) {
            f32x4 v;
#pragma unroll
            for (int r = 0; r < 4; ++r) v[r] = lsum[mt][r];
            *(f32x4*)&logitS[w * 32 + mt * 16 + quad * 4] = v;
        }
    }
    const float lg = logitS[w * 32 + (lane & 31)];

    // ---- softmax over the 32 edges ----
    float mx = lg;
#pragma unroll
    for (int off = 16; off; off >>= 1) mx = fmaxf(mx, __shfl_xor(mx, off, 64));
    const float e = __expf(lg - mx);
    float s = e;
#pragma unroll
    for (int off = 16; off; off >>= 1) s += __shfl_xor(s, off, 64);
    const float wgt = e / s;   // weight for edge k = lane & 31

    // ---- output from registers: out[d] = sum_k w_k * t[k][d] ----
    // Lane (m16,quad) holds t[mt*16+m16][quad*8+j] in Af[mt][2][j]
    //                  and t[mt*16+m16][32+quad*8+j] in Af[mt][3][j].
    float o0[8], o1[8];
#pragma unroll
    for (int j = 0; j < 8; ++j) { o0[j] = 0.f; o1[j] = 0.f; }
#pragma unroll
    for (int mt = 0; mt < 2; ++mt) {
        const float wv = __shfl(wgt, mt * 16 + m16, 64);
#pragma unroll
        for (int j = 0; j < 8; ++j) {
            o0[j] += wv * (float)Af[mt][2][j];
            o1[j] += wv * (float)Af[mt][3][j];
        }
    }
#pragma unroll
    for (int off = 1; off < 16; off <<= 1)
#pragma unroll
        for (int j = 0; j < 8; ++j) {
            o0[j] += __shfl_xor(o0[j], off, 64);
            o1[j] += __shfl_xor(o1[j], off, 64);
        }
    if (m16 == 0) {
        float* __restrict__ op =
            out + (((size_t)(tower * 3 + 1 + layer) * BB + b) * NF + w) * DIM;
        f32x4 v;
#pragma unroll
        for (int j = 0; j < 4; ++j) v[j] = o0[j];
        *(f32x4*)(op + quad * 8) = v;
#pragma unroll
        for (int j = 0; j < 4; ++j) v[j] = o0[4 + j];
        *(f32x4*)(op + quad * 8 + 4) = v;
#pragma unroll
        for (int j = 0; j < 4; ++j) v[j] = o1[j];
        *(f32x4*)(op + 32 + quad * 8) = v;
#pragma unroll
        for (int j = 0; j < 4; ++j) v[j] = o1[4 + j];
        *(f32x4*)(op + 32 + quad * 8 + 4) = v;
    }

    // origin row (written once, by layer==0 blocks)
    if (layer == 0)
        out[(((size_t)(tower * 3 + 0) * BB + b) * NF + w) * DIM + lane] = orv;
}

extern "C" void kernel_launch(void* const* d_in, const int* in_sizes, int n_in,
                              void* d_out, int out_size, void* d_ws, size_t ws_size,
                              hipStream_t stream) {
    const float* node_emb     = (const float*)d_in[0];
    // d_in[1] = relation_emb — dead in the reference computation
    const float* W1           = (const float*)d_in[2];
    const float* b1           = (const float*)d_in[3];
    const float* W2           = (const float*)d_in[4];
    const float* b2           = (const float*)d_in[5]; (void)b2; // cancels in softmax
    const int*   users        = (const int*)d_in[6];
    const int*   items        = (const int*)d_in[7];
    const int*   users_triple = (const int*)d_in[8];
    const int*   items_triple = (const int*)d_in[9];
    float* out = (float*)d_out;

    __bf16* w1t = (__bf16*)d_ws;   // 64*128*2 = 16 KB

    hipLaunchKernelGGL(prep_w1t, dim3(32), dim3(256), 0, stream, W1, w1t);
    hipLaunchKernelGGL(kgat_lds, dim3(2 * BB * NLAYER), dim3(256), 0, stream,
                       node_emb, w1t, b1, W2,
                       users, items, users_triple, items_triple, out);
}